// Round 15
// baseline (334.934 us; speedup 1.0000x reference)
//
#include <hip/hip_runtime.h>
#include <hip/hip_bf16.h>

#define B_  4096
#define T_  255
#define V_  32000
#define E_  64
#define H_  64
#define D1_ 32

#define NCT           2000   // V/16 col-tiles
#define NCHUNK        10
#define CT_PER_CHUNK  200    // NCT / NCHUNK
#define CT_PER_WAVE   50     // CT_PER_CHUNK / 4 waves

#define LOG2E  1.4426950408889634f

#if __has_builtin(__builtin_amdgcn_exp2f)
#define EXP2F __builtin_amdgcn_exp2f
#else
#define EXP2F exp2f
#endif

typedef __attribute__((ext_vector_type(8))) short bf16x8;   // 8 bf16 = 4 VGPR
typedef __attribute__((ext_vector_type(4))) float f32x4;

__device__ __forceinline__ ushort f2bf(float f) {
    __hip_bfloat16 h = __float2bfloat16(f);   // RNE
    return *reinterpret_cast<ushort*>(&h);
}

// Swizzled byte offset in a [16 rows][64 bf16] (128 B/row) h-tile.
__device__ __forceinline__ int hswz(int row, int colb) {
    return row * 128 + (colb ^ ((row & 7) << 4));
}

// ---------------------------------------------------------------------------
// Kernel 0 (merged prep):
//   blocks [0,1000):    emb fp32 -> bf16 (A-frag gatherable)
//   blocks [1000,1500): W2 repack -> bf16 B-frag-linear, prescaled by log2e
//   blocks [1500,1516): LSTM Wx/Wh -> bf16 B-frag-linear, exp2-prescaled
// ---------------------------------------------------------------------------
__global__ __launch_bounds__(256)
void prep_kernel(const float* __restrict__ emb, ushort* __restrict__ emb_bf,
                 const float* __restrict__ W2,  ushort* __restrict__ w2p,
                 const float* __restrict__ Wx,  const float* __restrict__ Wh,
                 ushort* __restrict__ wpack)
{
    if (blockIdx.x < 1000) {
        int i = blockIdx.x * 256 + threadIdx.x;      // over V*64/8 = 256000
        const float4 a = ((const float4*)emb)[i * 2];
        const float4 b = ((const float4*)emb)[i * 2 + 1];
        ushort t[8] = { f2bf(a.x), f2bf(a.y), f2bf(a.z), f2bf(a.w),
                        f2bf(b.x), f2bf(b.y), f2bf(b.z), f2bf(b.w) };
        *(ushort4*)(&emb_bf[i * 8])     = *(ushort4*)(&t[0]);
        *(ushort4*)(&emb_bf[i * 8 + 4]) = *(ushort4*)(&t[4]);
    } else if (blockIdx.x < 1500) {
        int t = (blockIdx.x - 1000) * 256 + threadIdx.x;   // over NCT*64
        if (t >= NCT * 64) return;
        int ct = t >> 6, l = t & 63;
        int kbase = (l >> 4) * 8, c = ct * 16 + (l & 15);
        ushort tmp[8];
        #pragma unroll
        for (int i = 0; i < 8; ++i)
            tmp[i] = f2bf(W2[(kbase + i) * V_ + c] * LOG2E);
        *(ushort4*)(&w2p[t * 8])     = *(ushort4*)(&tmp[0]);
        *(ushort4*)(&w2p[t * 8 + 4]) = *(ushort4*)(&tmp[4]);
    } else {
        int t = (blockIdx.x - 1500) * 256 + threadIdx.x;   // over 4*4*4*64=4096
        if (t >= 4096) return;
        int lane = t & 63;
        int s    = (t >> 6) & 3;
        int g    = (t >> 8) & 3;
        int w    = (t >> 10) & 3;
        int col  = g * 64 + w * 16 + (lane & 15);
        float sc = (g == 2) ? (2.f * LOG2E) : (-LOG2E);
        ushort tmp[8];
        #pragma unroll
        for (int i = 0; i < 8; ++i) {
            int k = s * 32 + (lane >> 4) * 8 + i;
            float v = (k < 64) ? Wx[k * 256 + col] : Wh[(k - 64) * 256 + col];
            tmp[i] = f2bf(v * sc);
        }
        *(ushort4*)(&wpack[t * 8])     = *(ushort4*)(&tmp[0]);
        *(ushort4*)(&wpack[t * 8 + 4]) = *(ushort4*)(&tmp[4]);
    }
}

// ===========================================================================
// LSTM, bf16 MFMA — R14 structure; activation now 7 trans ops/elem:
// common-denominator c-update (one rcp shared by f- and ig-terms):
//   c = [c*(1+Ei)(1+Eg) + (Eg-1)(1+Ef)] * rcp((1+Ef)(1+Ei)(1+Eg))
//   h = (Ec-1)*rcp((1+Eo)(1+Ec))
// 5 exp2 + 2 rcp. |z| <~ 6 here so products <= e^18 — fp32-safe.
// ===========================================================================
__global__ __launch_bounds__(256)
void lstm_mfma_kernel(const int* __restrict__ idx,
                      const ushort* __restrict__ emb_bf,
                      const ushort* __restrict__ wpack,
                      const float* __restrict__ b,
                      const float* __restrict__ W1,
                      const float* __restrict__ b1,
                      ushort* __restrict__ out32bf)
{
    __shared__ __align__(16) char hbuf[2][2048];   // [buf][16 rows][64 bf16]
    __shared__ int idxs[16 * 257];                 // [row][t], stride 257

    const int tid  = threadIdx.x;
    const int lane = tid & 63;
    const int w    = tid >> 6;          // unit group
    const int r0   = blockIdx.x * 16;
    const int lrow = lane & 15;
    const int lhi  = lane >> 4;
    const int jcol = w * 16 + lrow;

    // persistent B fragments — coalesced b128 loads from wpack
    bf16x8 bw[16];
    #pragma unroll
    for (int g = 0; g < 4; ++g)
        #pragma unroll
        for (int s = 0; s < 4; ++s)
            bw[g * 4 + s] = *(const bf16x8*)(wpack + (((w * 4 + g) * 4 + s) * 64 + lane) * 8);

    f32x4 bsp[4];
    #pragma unroll
    for (int g = 0; g < 4; ++g) {
        const float sc = (g == 2) ? (2.f * LOG2E) : (-LOG2E);
        const float bv = b[g * 64 + jcol] * sc;
        bsp[g] = (f32x4){bv, bv, bv, bv};
    }

    // W1 B-frags for the fused head1 epilogue (waves 0,1 only)
    bf16x8 bw1[2];
    float b1v = 0.f;
    if (w < 2) {
        const int col = w * 16 + lrow;
        b1v = b1[col];
        #pragma unroll
        for (int s = 0; s < 2; ++s) {
            bf16x8 f;
            #pragma unroll
            for (int i = 0; i < 8; ++i)
                f[i] = (short)f2bf(W1[(s * 32 + lhi * 8 + i) * D1_ + col]);
            bw1[s] = f;
        }
    }

    {
        const int row = tid >> 4, tc = tid & 15;
        #pragma unroll
        for (int k = 0; k < 16; ++k) {
            int t = k * 16 + tc;
            if (t < T_) idxs[row * 257 + t] = idx[(r0 + row) * T_ + t];
        }
        ((float2*)hbuf[0])[tid] = make_float2(0.f, 0.f);
    }
    __syncthreads();

    // dual-slot x pipeline (no register rotation: true 2-step distance)
    bf16x8 xe0, xe1, xo0, xo1;
    {
        int iv = idxs[lrow * 257 + 0];
        xe0 = *(const bf16x8*)(emb_bf + iv * 64 + lhi * 8);
        xe1 = *(const bf16x8*)(emb_bf + iv * 64 + 32 + lhi * 8);
        iv = idxs[lrow * 257 + 1];
        xo0 = *(const bf16x8*)(emb_bf + iv * 64 + lhi * 8);
        xo1 = *(const bf16x8*)(emb_bf + iv * 64 + 32 + lhi * 8);
    }

    float cst[4]  = {0.f, 0.f, 0.f, 0.f};

    auto do_step = [&](int t, bf16x8& x0, bf16x8& x1) {
        const int p = t & 1;
        bf16x8 ah2 = *(const bf16x8*)(&hbuf[p][hswz(lrow, lhi * 16)]);
        bf16x8 ah3 = *(const bf16x8*)(&hbuf[p][hswz(lrow, 64 + lhi * 16)]);

        // z = bias + [x|h] @ W : 4 parallel gate chains, depth 4
        f32x4 z[4];
        #pragma unroll
        for (int g = 0; g < 4; ++g)
            z[g] = __builtin_amdgcn_mfma_f32_16x16x32_bf16(x0, bw[g * 4 + 0], bsp[g], 0, 0, 0);
        #pragma unroll
        for (int g = 0; g < 4; ++g)
            z[g] = __builtin_amdgcn_mfma_f32_16x16x32_bf16(x1, bw[g * 4 + 1], z[g], 0, 0, 0);
        #pragma unroll
        for (int g = 0; g < 4; ++g)
            z[g] = __builtin_amdgcn_mfma_f32_16x16x32_bf16(ah2, bw[g * 4 + 2], z[g], 0, 0, 0);
        #pragma unroll
        for (int g = 0; g < 4; ++g)
            z[g] = __builtin_amdgcn_mfma_f32_16x16x32_bf16(ah3, bw[g * 4 + 3], z[g], 0, 0, 0);

        // reload THIS slot for t+2 (in flight across 2 raw barriers)
        if (t + 2 < T_) {
            int iv = idxs[lrow * 257 + (t + 2)];
            x0 = *(const bf16x8*)(emb_bf + iv * 64 + lhi * 8);
            x1 = *(const bf16x8*)(emb_bf + iv * 64 + 32 + lhi * 8);
        }

        // activation, 7-trans form (wave-local)
        #pragma unroll
        for (int r = 0; r < 4; ++r) {
            float Ei = EXP2F(z[0][r]);               // e^-zi
            float Ef = EXP2F(z[1][r]);               // e^-zf
            float Eg = EXP2F(z[2][r]);               // e^{2 zg}
            float Eo = EXP2F(z[3][r]);               // e^-zo
            float pig = (1.f + Ei) * (1.f + Eg);
            float pf  = 1.f + Ef;
            float num = cst[r] * pig + (Eg - 1.f) * pf;
            float cn  = num * __builtin_amdgcn_rcpf(pf * pig);
            cst[r] = cn;
            float Ec = EXP2F(cn * (2.f * LOG2E));    // e^{2c}
            float hn = (Ec - 1.f) * __builtin_amdgcn_rcpf((1.f + Eo) * (1.f + Ec));
            const int row = lhi * 4 + r;
            *(ushort*)(&hbuf[p ^ 1][hswz(row, 2 * jcol)]) = f2bf(hn);
        }

        // LDS-only fence + raw barrier (global loads stay in flight)
        asm volatile("s_waitcnt lgkmcnt(0)\n\ts_barrier" ::: "memory");
    };

    for (int t = 0; t + 1 < T_; t += 2) {
        do_step(t,     xe0, xe1);
        do_step(t + 1, xo0, xo1);
    }
    do_step(T_ - 1, xe0, xe1);   // T_=255 odd: tail is an even-slot step

    // ---- fused head1: out32 = relu(h(T-1) @ W1 + b1), h from hbuf[1] ----
    if (w < 2) {
        bf16x8 e0 = *(const bf16x8*)(&hbuf[1][hswz(lrow, lhi * 16)]);
        bf16x8 e1 = *(const bf16x8*)(&hbuf[1][hswz(lrow, 64 + lhi * 16)]);
        f32x4 zz = (f32x4){b1v, b1v, b1v, b1v};
        zz = __builtin_amdgcn_mfma_f32_16x16x32_bf16(e0, bw1[0], zz, 0, 0, 0);
        zz = __builtin_amdgcn_mfma_f32_16x16x32_bf16(e1, bw1[1], zz, 0, 0, 0);
        #pragma unroll
        for (int r = 0; r < 4; ++r)
            out32bf[(r0 + lhi * 4 + r) * D1_ + w * 16 + lrow] =
                f2bf(fmaxf(zz[r], 0.f));
    }
}

// ---------------------------------------------------------------------------
// Kernel 3: logits = out32 @ W2 + b2, softmax over V, via MFMA.
// w2p prescaled by log2e; b2 scaled in-kernel -> exp is one v_exp_f32.
// unroll 4: four independent load->MFMA->exp chains hide L2 latency.
// ---------------------------------------------------------------------------
template <int PASS>
__global__ __launch_bounds__(256)
void head2_mfma_kernel(const ushort* __restrict__ out32bf,
                       const ushort* __restrict__ w2p,
                       const float* __restrict__ b2,
                       float* __restrict__ partial,   // [B][NCHUNK]
                       float* __restrict__ out)
{
    __shared__ float red[4][16];
    __shared__ float sinvs[16];

    const int tid  = threadIdx.x;
    const int lane = tid & 63;
    const int w    = tid >> 6;
    const int lrow = lane & 15;
    const int lhi  = lane >> 4;
    const int r0    = blockIdx.x * 16;
    const int chunk = blockIdx.y;

    if (PASS == 2) {
        if (tid < 16) {
            float s = 0.f;
            #pragma unroll
            for (int c = 0; c < NCHUNK; ++c) s += partial[(r0 + tid) * NCHUNK + c];
            sinvs[tid] = 1.f / s;
        }
        __syncthreads();
    }

    const bf16x8 A = *(const bf16x8*)(out32bf + (r0 + lrow) * D1_ + lhi * 8);

    float sacc[4] = {0.f, 0.f, 0.f, 0.f};
    float si[4];
    if (PASS == 2) {
        #pragma unroll
        for (int r = 0; r < 4; ++r) si[r] = sinvs[lhi * 4 + r];
    }

    const int ct0 = chunk * CT_PER_CHUNK + w * CT_PER_WAVE;
    #pragma unroll 4
    for (int i = 0; i < CT_PER_WAVE; ++i) {
        const int ct = ct0 + i;
        const bf16x8 Bf = *(const bf16x8*)(w2p + ct * 512 + lane * 8);
        f32x4 z = __builtin_amdgcn_mfma_f32_16x16x32_bf16(A, Bf, (f32x4){0.f, 0.f, 0.f, 0.f}, 0, 0, 0);
        const float b2s = b2[ct * 16 + lrow] * LOG2E;
        #pragma unroll
        for (int r = 0; r < 4; ++r) {
            float e = EXP2F(z[r] + b2s);
            if (PASS == 1) sacc[r] += e;
            else out[(size_t)(r0 + lhi * 4 + r) * V_ + ct * 16 + lrow] = e * si[r];
        }
    }

    if (PASS == 1) {
        #pragma unroll
        for (int r = 0; r < 4; ++r) {
            float v = sacc[r];
            #pragma unroll
            for (int off = 1; off < 16; off <<= 1) v += __shfl_xor(v, off, 16);
            if (lrow == 0) red[w][lhi * 4 + r] = v;
        }
        __syncthreads();
        if (tid < 16)
            partial[(r0 + tid) * NCHUNK + chunk] =
                red[0][tid] + red[1][tid] + red[2][tid] + red[3][tid];
    }
}

// ---------------------------------------------------------------------------
extern "C" void kernel_launch(void* const* d_in, const int* in_sizes, int n_in,
                              void* d_out, int out_size, void* d_ws, size_t ws_size,
                              hipStream_t stream)
{
    (void)in_sizes; (void)n_in; (void)out_size; (void)ws_size;

    const int*   idx = (const int*)  d_in[0];
    const float* emb = (const float*)d_in[1];
    const float* Wx  = (const float*)d_in[2];
    const float* Wh  = (const float*)d_in[3];
    const float* bl  = (const float*)d_in[4];
    const float* W1  = (const float*)d_in[5];
    const float* b1  = (const float*)d_in[6];
    const float* W2  = (const float*)d_in[7];
    const float* b2  = (const float*)d_in[8];
    float* out = (float*)d_out;

    float*  ws      = (float*)d_ws;
    ushort* out32bf = (ushort*)ws;                           // 131072 us
    ushort* w2p     = (ushort*)(ws + 65536);                 // 1024000 us
    float*  part    = ws + 65536 + 512000;                   // 40960 f32
    ushort* emb_bf  = (ushort*)(ws + 65536 + 512000 + 40960);  // 2048000 us
    ushort* wpack   = (ushort*)(ws + 65536 + 512000 + 40960 + 1024000);  // 32768 us

    prep_kernel<<<1516, 256, 0, stream>>>(emb, emb_bf, W2, w2p, Wx, Wh, wpack);
    lstm_mfma_kernel<<<256, 256, 0, stream>>>(idx, emb_bf, wpack, bl, W1, b1, out32bf);

    dim3 g3(B_ / 16, NCHUNK);
    head2_mfma_kernel<1><<<g3, 256, 0, stream>>>(out32bf, w2p, b2, part, out);
    head2_mfma_kernel<2><<<g3, 256, 0, stream>>>(out32bf, w2p, b2, part, out);
}

// Round 16
// 305.028 us; speedup vs baseline: 1.0980x; 1.0980x over previous
//
#include <hip/hip_runtime.h>
#include <hip/hip_bf16.h>

#define B_  4096
#define T_  255
#define V_  32000
#define E_  64
#define H_  64
#define D1_ 32

#define NCT           2000   // V/16 col-tiles
#define NCHUNK        10
#define CT_PER_CHUNK  200    // NCT / NCHUNK
#define CT_PER_WAVE   50     // CT_PER_CHUNK / 4 waves

#define LOG2E  1.4426950408889634f

#if __has_builtin(__builtin_amdgcn_exp2f)
#define EXP2F __builtin_amdgcn_exp2f
#else
#define EXP2F exp2f
#endif

typedef __attribute__((ext_vector_type(8))) short bf16x8;   // 8 bf16 = 4 VGPR
typedef __attribute__((ext_vector_type(4))) float f32x4;

__device__ __forceinline__ ushort f2bf(float f) {
    __hip_bfloat16 h = __float2bfloat16(f);   // RNE
    return *reinterpret_cast<ushort*>(&h);
}

// Swizzled byte offset in a [16 rows][64 bf16] (128 B/row) h-tile.
__device__ __forceinline__ int hswz(int row, int colb) {
    return row * 128 + (colb ^ ((row & 7) << 4));
}

// ---------------------------------------------------------------------------
// Kernel 0 (merged prep):
//   blocks [0,1000):    emb fp32 -> bf16 (A-frag gatherable)
//   blocks [1000,1500): W2 repack -> bf16 B-frag-linear, prescaled by log2e
//   blocks [1500,1516): LSTM Wx/Wh -> bf16 B-frag-linear, exp2-prescaled
// ---------------------------------------------------------------------------
__global__ __launch_bounds__(256)
void prep_kernel(const float* __restrict__ emb, ushort* __restrict__ emb_bf,
                 const float* __restrict__ W2,  ushort* __restrict__ w2p,
                 const float* __restrict__ Wx,  const float* __restrict__ Wh,
                 ushort* __restrict__ wpack)
{
    if (blockIdx.x < 1000) {
        int i = blockIdx.x * 256 + threadIdx.x;      // over V*64/8 = 256000
        const float4 a = ((const float4*)emb)[i * 2];
        const float4 b = ((const float4*)emb)[i * 2 + 1];
        ushort t[8] = { f2bf(a.x), f2bf(a.y), f2bf(a.z), f2bf(a.w),
                        f2bf(b.x), f2bf(b.y), f2bf(b.z), f2bf(b.w) };
        *(ushort4*)(&emb_bf[i * 8])     = *(ushort4*)(&t[0]);
        *(ushort4*)(&emb_bf[i * 8 + 4]) = *(ushort4*)(&t[4]);
    } else if (blockIdx.x < 1500) {
        int t = (blockIdx.x - 1000) * 256 + threadIdx.x;   // over NCT*64
        if (t >= NCT * 64) return;
        int ct = t >> 6, l = t & 63;
        int kbase = (l >> 4) * 8, c = ct * 16 + (l & 15);
        ushort tmp[8];
        #pragma unroll
        for (int i = 0; i < 8; ++i)
            tmp[i] = f2bf(W2[(kbase + i) * V_ + c] * LOG2E);
        *(ushort4*)(&w2p[t * 8])     = *(ushort4*)(&tmp[0]);
        *(ushort4*)(&w2p[t * 8 + 4]) = *(ushort4*)(&tmp[4]);
    } else {
        int t = (blockIdx.x - 1500) * 256 + threadIdx.x;   // over 4*4*4*64=4096
        if (t >= 4096) return;
        int lane = t & 63;
        int s    = (t >> 6) & 3;
        int g    = (t >> 8) & 3;
        int w    = (t >> 10) & 3;
        int col  = g * 64 + w * 16 + (lane & 15);
        float sc = (g == 2) ? (2.f * LOG2E) : (-LOG2E);
        ushort tmp[8];
        #pragma unroll
        for (int i = 0; i < 8; ++i) {
            int k = s * 32 + (lane >> 4) * 8 + i;
            float v = (k < 64) ? Wx[k * 256 + col] : Wh[(k - 64) * 256 + col];
            tmp[i] = f2bf(v * sc);
        }
        *(ushort4*)(&wpack[t * 8])     = *(ushort4*)(&tmp[0]);
        *(ushort4*)(&wpack[t * 8 + 4]) = *(ushort4*)(&tmp[4]);
    }
}

// ===========================================================================
// LSTM, bf16 MFMA — R14 structure (revert of R15): activation 8 trans/elem:
// with Ei=e^-zi, Ef=e^-zf, Eg=e^{2zg}, Eo=e^-zo, Ec=e^{2c} (scales folded
// into the MFMA weights), using sigma(a)*tanh(b) = (Eb-1)*rcp((1+Ea)(1+Eb)):
//   c = c*rcp(1+Ef) + (Eg-1)*rcp((1+Ei)(1+Eg))     (two INDEPENDENT rcps)
//   h = (Ec-1)*rcp((1+Eo)(1+Ec))
// 5 exp2 + 3 rcp. All fp32-safe (products <= ~1e9).
// ===========================================================================
__global__ __launch_bounds__(256)
void lstm_mfma_kernel(const int* __restrict__ idx,
                      const ushort* __restrict__ emb_bf,
                      const ushort* __restrict__ wpack,
                      const float* __restrict__ b,
                      const float* __restrict__ W1,
                      const float* __restrict__ b1,
                      ushort* __restrict__ out32bf)
{
    __shared__ __align__(16) char hbuf[2][2048];   // [buf][16 rows][64 bf16]
    __shared__ int idxs[16 * 257];                 // [row][t], stride 257

    const int tid  = threadIdx.x;
    const int lane = tid & 63;
    const int w    = tid >> 6;          // unit group
    const int r0   = blockIdx.x * 16;
    const int lrow = lane & 15;
    const int lhi  = lane >> 4;
    const int jcol = w * 16 + lrow;

    // persistent B fragments — coalesced b128 loads from wpack
    bf16x8 bw[16];
    #pragma unroll
    for (int g = 0; g < 4; ++g)
        #pragma unroll
        for (int s = 0; s < 4; ++s)
            bw[g * 4 + s] = *(const bf16x8*)(wpack + (((w * 4 + g) * 4 + s) * 64 + lane) * 8);

    f32x4 bsp[4];
    #pragma unroll
    for (int g = 0; g < 4; ++g) {
        const float sc = (g == 2) ? (2.f * LOG2E) : (-LOG2E);
        const float bv = b[g * 64 + jcol] * sc;
        bsp[g] = (f32x4){bv, bv, bv, bv};
    }

    // W1 B-frags for the fused head1 epilogue (waves 0,1 only)
    bf16x8 bw1[2];
    float b1v = 0.f;
    if (w < 2) {
        const int col = w * 16 + lrow;
        b1v = b1[col];
        #pragma unroll
        for (int s = 0; s < 2; ++s) {
            bf16x8 f;
            #pragma unroll
            for (int i = 0; i < 8; ++i)
                f[i] = (short)f2bf(W1[(s * 32 + lhi * 8 + i) * D1_ + col]);
            bw1[s] = f;
        }
    }

    {
        const int row = tid >> 4, tc = tid & 15;
        #pragma unroll
        for (int k = 0; k < 16; ++k) {
            int t = k * 16 + tc;
            if (t < T_) idxs[row * 257 + t] = idx[(r0 + row) * T_ + t];
        }
        ((float2*)hbuf[0])[tid] = make_float2(0.f, 0.f);
    }
    __syncthreads();

    // dual-slot x pipeline (no register rotation: true 2-step distance)
    bf16x8 xe0, xe1, xo0, xo1;
    {
        int iv = idxs[lrow * 257 + 0];
        xe0 = *(const bf16x8*)(emb_bf + iv * 64 + lhi * 8);
        xe1 = *(const bf16x8*)(emb_bf + iv * 64 + 32 + lhi * 8);
        iv = idxs[lrow * 257 + 1];
        xo0 = *(const bf16x8*)(emb_bf + iv * 64 + lhi * 8);
        xo1 = *(const bf16x8*)(emb_bf + iv * 64 + 32 + lhi * 8);
    }

    float cst[4]  = {0.f, 0.f, 0.f, 0.f};

    auto do_step = [&](int t, bf16x8& x0, bf16x8& x1) {
        const int p = t & 1;
        bf16x8 ah2 = *(const bf16x8*)(&hbuf[p][hswz(lrow, lhi * 16)]);
        bf16x8 ah3 = *(const bf16x8*)(&hbuf[p][hswz(lrow, 64 + lhi * 16)]);

        // z = bias + [x|h] @ W : 4 parallel gate chains, depth 4
        f32x4 z[4];
        #pragma unroll
        for (int g = 0; g < 4; ++g)
            z[g] = __builtin_amdgcn_mfma_f32_16x16x32_bf16(x0, bw[g * 4 + 0], bsp[g], 0, 0, 0);
        #pragma unroll
        for (int g = 0; g < 4; ++g)
            z[g] = __builtin_amdgcn_mfma_f32_16x16x32_bf16(x1, bw[g * 4 + 1], z[g], 0, 0, 0);
        #pragma unroll
        for (int g = 0; g < 4; ++g)
            z[g] = __builtin_amdgcn_mfma_f32_16x16x32_bf16(ah2, bw[g * 4 + 2], z[g], 0, 0, 0);
        #pragma unroll
        for (int g = 0; g < 4; ++g)
            z[g] = __builtin_amdgcn_mfma_f32_16x16x32_bf16(ah3, bw[g * 4 + 3], z[g], 0, 0, 0);

        // reload THIS slot for t+2 (in flight across 2 raw barriers)
        if (t + 2 < T_) {
            int iv = idxs[lrow * 257 + (t + 2)];
            x0 = *(const bf16x8*)(emb_bf + iv * 64 + lhi * 8);
            x1 = *(const bf16x8*)(emb_bf + iv * 64 + 32 + lhi * 8);
        }

        // activation, 8-trans form (wave-local)
        #pragma unroll
        for (int r = 0; r < 4; ++r) {
            float Ei = EXP2F(z[0][r]);               // e^-zi
            float Ef = EXP2F(z[1][r]);               // e^-zf
            float Eg = EXP2F(z[2][r]);               // e^{2 zg}
            float Eo = EXP2F(z[3][r]);               // e^-zo
            float ig = (Eg - 1.f) * __builtin_amdgcn_rcpf((1.f + Ei) * (1.f + Eg));
            float cn = cst[r] * __builtin_amdgcn_rcpf(1.f + Ef) + ig;
            cst[r] = cn;
            float Ec = EXP2F(cn * (2.f * LOG2E));    // e^{2c}
            float hn = (Ec - 1.f) * __builtin_amdgcn_rcpf((1.f + Eo) * (1.f + Ec));
            const int row = lhi * 4 + r;
            *(ushort*)(&hbuf[p ^ 1][hswz(row, 2 * jcol)]) = f2bf(hn);
        }

        // LDS-only fence + raw barrier (global loads stay in flight)
        asm volatile("s_waitcnt lgkmcnt(0)\n\ts_barrier" ::: "memory");
    };

    for (int t = 0; t + 1 < T_; t += 2) {
        do_step(t,     xe0, xe1);
        do_step(t + 1, xo0, xo1);
    }
    do_step(T_ - 1, xe0, xe1);   // T_=255 odd: tail is an even-slot step

    // ---- fused head1: out32 = relu(h(T-1) @ W1 + b1), h from hbuf[1] ----
    if (w < 2) {
        bf16x8 e0 = *(const bf16x8*)(&hbuf[1][hswz(lrow, lhi * 16)]);
        bf16x8 e1 = *(const bf16x8*)(&hbuf[1][hswz(lrow, 64 + lhi * 16)]);
        f32x4 zz = (f32x4){b1v, b1v, b1v, b1v};
        zz = __builtin_amdgcn_mfma_f32_16x16x32_bf16(e0, bw1[0], zz, 0, 0, 0);
        zz = __builtin_amdgcn_mfma_f32_16x16x32_bf16(e1, bw1[1], zz, 0, 0, 0);
        #pragma unroll
        for (int r = 0; r < 4; ++r)
            out32bf[(r0 + lhi * 4 + r) * D1_ + w * 16 + lrow] =
                f2bf(fmaxf(zz[r], 0.f));
    }
}

// ---------------------------------------------------------------------------
// Kernel 3: logits = out32 @ W2 + b2, softmax over V, via MFMA.
// w2p prescaled by log2e; b2 scaled in-kernel -> exp is one v_exp_f32.
// unroll 2 (R14 setting; unroll 4 measured worse in R15).
// ---------------------------------------------------------------------------
template <int PASS>
__global__ __launch_bounds__(256)
void head2_mfma_kernel(const ushort* __restrict__ out32bf,
                       const ushort* __restrict__ w2p,
                       const float* __restrict__ b2,
                       float* __restrict__ partial,   // [B][NCHUNK]
                       float* __restrict__ out)
{
    __shared__ float red[4][16];
    __shared__ float sinvs[16];

    const int tid  = threadIdx.x;
    const int lane = tid & 63;
    const int w    = tid >> 6;
    const int lrow = lane & 15;
    const int lhi  = lane >> 4;
    const int r0    = blockIdx.x * 16;
    const int chunk = blockIdx.y;

    if (PASS == 2) {
        if (tid < 16) {
            float s = 0.f;
            #pragma unroll
            for (int c = 0; c < NCHUNK; ++c) s += partial[(r0 + tid) * NCHUNK + c];
            sinvs[tid] = 1.f / s;
        }
        __syncthreads();
    }

    const bf16x8 A = *(const bf16x8*)(out32bf + (r0 + lrow) * D1_ + lhi * 8);

    float sacc[4] = {0.f, 0.f, 0.f, 0.f};
    float si[4];
    if (PASS == 2) {
        #pragma unroll
        for (int r = 0; r < 4; ++r) si[r] = sinvs[lhi * 4 + r];
    }

    const int ct0 = chunk * CT_PER_CHUNK + w * CT_PER_WAVE;
    #pragma unroll 2
    for (int i = 0; i < CT_PER_WAVE; ++i) {
        const int ct = ct0 + i;
        const bf16x8 Bf = *(const bf16x8*)(w2p + ct * 512 + lane * 8);
        f32x4 z = __builtin_amdgcn_mfma_f32_16x16x32_bf16(A, Bf, (f32x4){0.f, 0.f, 0.f, 0.f}, 0, 0, 0);
        const float b2s = b2[ct * 16 + lrow] * LOG2E;
        #pragma unroll
        for (int r = 0; r < 4; ++r) {
            float e = EXP2F(z[r] + b2s);
            if (PASS == 1) sacc[r] += e;
            else out[(size_t)(r0 + lhi * 4 + r) * V_ + ct * 16 + lrow] = e * si[r];
        }
    }

    if (PASS == 1) {
        #pragma unroll
        for (int r = 0; r < 4; ++r) {
            float v = sacc[r];
            #pragma unroll
            for (int off = 1; off < 16; off <<= 1) v += __shfl_xor(v, off, 16);
            if (lrow == 0) red[w][lhi * 4 + r] = v;
        }
        __syncthreads();
        if (tid < 16)
            partial[(r0 + tid) * NCHUNK + chunk] =
                red[0][tid] + red[1][tid] + red[2][tid] + red[3][tid];
    }
}

// ---------------------------------------------------------------------------
extern "C" void kernel_launch(void* const* d_in, const int* in_sizes, int n_in,
                              void* d_out, int out_size, void* d_ws, size_t ws_size,
                              hipStream_t stream)
{
    (void)in_sizes; (void)n_in; (void)out_size; (void)ws_size;

    const int*   idx = (const int*)  d_in[0];
    const float* emb = (const float*)d_in[1];
    const float* Wx  = (const float*)d_in[2];
    const float* Wh  = (const float*)d_in[3];
    const float* bl  = (const float*)d_in[4];
    const float* W1  = (const float*)d_in[5];
    const float* b1  = (const float*)d_in[6];
    const float* W2  = (const float*)d_in[7];
    const float* b2  = (const float*)d_in[8];
    float* out = (float*)d_out;

    float*  ws      = (float*)d_ws;
    ushort* out32bf = (ushort*)ws;                           // 131072 us
    ushort* w2p     = (ushort*)(ws + 65536);                 // 1024000 us
    float*  part    = ws + 65536 + 512000;                   // 40960 f32
    ushort* emb_bf  = (ushort*)(ws + 65536 + 512000 + 40960);  // 2048000 us
    ushort* wpack   = (ushort*)(ws + 65536 + 512000 + 40960 + 1024000);  // 32768 us

    prep_kernel<<<1516, 256, 0, stream>>>(emb, emb_bf, W2, w2p, Wx, Wh, wpack);
    lstm_mfma_kernel<<<256, 256, 0, stream>>>(idx, emb_bf, wpack, bl, W1, b1, out32bf);

    dim3 g3(B_ / 16, NCHUNK);
    head2_mfma_kernel<1><<<g3, 256, 0, stream>>>(out32bf, w2p, b2, part, out);
    head2_mfma_kernel<2><<<g3, 256, 0, stream>>>(out32bf, w2p, b2, part, out);
}